// Round 7
// baseline (128.664 us; speedup 1.0000x reference)
//
#include <hip/hip_runtime.h>
#include <stdint.h>
#include <stddef.h>

// Problem constants (reference: M=16, K=8192, N=8192, GROUP=128)
#define MM 16
#define KK 8192
#define NN 8192
#define GROUP_SZ 128
#define NGROUP 64
#define KPACK 1024           // K/8 packed int32 per output row
#define NT 128               // 64-col n-tiles
#define KQN 8                // k-split factor
#define KSL (KK / KQN)       // 1024 k per block
#define GPB (KSL / GROUP_SZ) // 8 groups per block
#define CPB 64               // n-cols per block

typedef _Float16 half8_t __attribute__((ext_vector_type(8)));
typedef _Float16 half2_t __attribute__((ext_vector_type(2)));
typedef float float4_t __attribute__((ext_vector_type(4)));
typedef uint32_t uint4_t __attribute__((ext_vector_type(4)));

// XOR swizzle on 16B-chunk index within a 256-chunk x-stage buffer.
// Validated in rounds 3-6 (write & read beats both <=2-way, free).
__device__ __forceinline__ int swz(int fc) {
    return fc ^ (((fc >> 3) ^ (fc >> 6)) & 7);
}

// ---------------------------------------------------------------------------
// Reduce: out[m][n] = bias[n] + sum_kq ws[kq][m][n].  128 blocks x 256 thr,
// float4 per thread. Reads 4MB + 32KB, writes 512KB (~1.5us).
// ---------------------------------------------------------------------------
__global__ __launch_bounds__(256) void wq_reduce(const float* __restrict__ ws,
                                                 const float* __restrict__ bias,
                                                 float* __restrict__ out) {
    const int idx = (blockIdx.x * 256 + threadIdx.x) * 4;
    const int m   = idx >> 13;          // NN = 2^13
    const int nn  = idx & (NN - 1);
    float4_t v = *(const float4_t*)(bias + nn);
    #pragma unroll
    for (int kq = 0; kq < KQN; ++kq) {
        const float4_t p = *(const float4_t*)(ws + ((size_t)(kq * MM + m) * NN + nn));
        v[0] += p[0]; v[1] += p[1]; v[2] += p[2]; v[3] += p[3];
    }
    *(float4_t*)(out + (size_t)m * NN + nn) = v;
}

// ---------------------------------------------------------------------------
// 1024 blocks = 128 n-tiles x 8 k-splits; 256 threads (4 waves).
// Block (nt, kq): cols [nt*64, +64), k [kq*1024, +1024) = 8 groups.
//
// qweight: cooperatively streamed into LDS as CONTIGUOUS 512B runs (validated
//   in round 6: kernel streams at 3.2TB/s vs 0.47 for the strided gather).
// x: staged once per block (shared by all 4 waves), double-buffered,
//   1 barrier/group; validated fragment order/swizzle.
// Math per group identical to the validated round-3..6 kernels (rte f16
// cvt, fdot2 exact zero-point sums, f32 accumulators, deferred shuffles).
//
// vs round 6: NO ATOMICS. Round 6's 1M cross-XCD atomicAdds caused ~160MB
// of HBM line-RMW traffic (FETCH 75MB / WRITE 92MB vs 38MB ideal) and
// serialized at 40% BW. Partials now go to workspace with plain coalesced
// stores (4MB); wq_reduce folds them with bias.
// ---------------------------------------------------------------------------
__global__ __launch_bounds__(256, 4) void wq_main(
        const float* __restrict__ x,
        const int* __restrict__ qweight,
        const float* __restrict__ scales,
        const float* __restrict__ zeros,
        float* __restrict__ ws) {
    __shared__ alignas(16) int      qlds[CPB * 128];     // 32 KB (64 rows x 512B)
    __shared__ alignas(16) _Float16 xstage[2 * 2048];    // 8 KB (2 x 4KB bufs)

    const int t    = threadIdx.x;
    const int bid  = blockIdx.x;
    const int nt   = bid & (NT - 1);   // consecutive bids -> different XCDs
    const int kq   = bid >> 7;
    const int w    = t >> 6;
    const int lane = t & 63;
    const int nlo  = lane & 15;
    const int quad = lane >> 4;
    const int n    = nt * CPB + w * 16 + nlo;

    // ---- cooperative qweight stream: 2048 chunks of 16B; chunk c ----
    // rr = c>>5 (row 0..63), b = c&31 (16B piece within 512B row-slice).
    uint4_t qv[8];
    #pragma unroll
    for (int i = 0; i < 8; ++i) {
        const int c  = i * 256 + t;
        const int rr = c >> 5, b = c & 31;
        qv[i] = *(const uint4_t*)(qweight + (size_t)(nt * CPB + rr) * KPACK
                                  + kq * (KSL / 8) + b * 4);
    }

    // ---- x group-0 load (thread t -> row xr, k-oct xo) ----
    const int xr = t >> 4, xo = t & 15;
    const float* xbase = x + (size_t)xr * KK + kq * KSL + xo * 8;
    float4_t pxa = *(const float4_t*)(xbase);
    float4_t pxb = *(const float4_t*)(xbase + 4);

    // ---- hoisted per-group scale / zero-correction coefficients ----
    float sA[GPB], cA[GPB];
    #pragma unroll
    for (int g = 0; g < GPB; ++g) {
        const size_t ro = (size_t)(kq * GPB + g) * NN + n;
        const float sg = scales[ro];
        const float zg = zeros[ro];
        sA[g] = sg;
        cA[g] = zg - 1024.0f * sg;
    }

    // ---- qlds write: row-slice-major, per-row XOR swizzle ----
    #pragma unroll
    for (int i = 0; i < 8; ++i) {
        const int c  = i * 256 + t;
        const int rr = c >> 5, b = c & 31;
        *(uint4_t*)((char*)qlds + ((rr * 32 + (b ^ (rr & 7))) << 4)) = qv[i];
    }

    // ---- stage x group 0 into buf0 (validated fragment order/swizzle) ----
    const int wchunk = swz((xo & 3) * 64 + (xo >> 2) * 16 + xr);
    half8_t* xb = (half8_t*)xstage;
    {
        half8_t st;
        st[0] = (_Float16)pxa[0]; st[1] = (_Float16)pxb[0];
        st[2] = (_Float16)pxa[1]; st[3] = (_Float16)pxb[1];
        st[4] = (_Float16)pxa[2]; st[5] = (_Float16)pxb[2];
        st[6] = (_Float16)pxa[3]; st[7] = (_Float16)pxb[3];
        xb[wchunk] = st;
    }
    // prefetch x group 1
    pxa = *(const float4_t*)(xbase + GROUP_SZ);
    pxb = *(const float4_t*)(xbase + GROUP_SZ + 4);

    int rfc[4];
    #pragma unroll
    for (int j = 0; j < 4; ++j)
        rfc[j] = swz(j * 64 + lane);
    const int qrr = w * 16 + nlo;  // this lane's qlds row

    float4_t outacc = {0.f, 0.f, 0.f, 0.f};
    float pg[GPB];

    #pragma unroll
    for (int g = 0; g < GPB; ++g) {
        // barrier: (a) makes buf[g&1] writes visible, (b) guarantees the
        // previous group's reads of buf[(g+1)&1] are done before overwrite
        __syncthreads();

        if (g + 1 < GPB) {
            half8_t st;
            st[0] = (_Float16)pxa[0]; st[1] = (_Float16)pxb[0];
            st[2] = (_Float16)pxa[1]; st[3] = (_Float16)pxb[1];
            st[4] = (_Float16)pxa[2]; st[5] = (_Float16)pxb[2];
            st[6] = (_Float16)pxa[3]; st[7] = (_Float16)pxb[3];
            xb[(((g + 1) & 1) << 8) + wchunk] = st;
        }
        if (g + 2 < GPB) {
            pxa = *(const float4_t*)(xbase + (g + 2) * GROUP_SZ);
            pxb = *(const float4_t*)(xbase + (g + 2) * GROUP_SZ + 4);
        }

        // B: one ds_read_b128 = 4 packed int32 (k-chunk quad*32..+32)
        const uint4_t bw = *(const uint4_t*)((const char*)qlds
            + ((qrr * 32 + ((g * 4 + quad) ^ (qrr & 7))) << 4));

        // A fragments from the shared staged buffer
        half8_t af[4];
        #pragma unroll
        for (int j = 0; j < 4; ++j)
            af[j] = xb[((g & 1) << 8) + rfc[j]];

        float4_t ge = {0.f, 0.f, 0.f, 0.f};
        float4_t go = {0.f, 0.f, 0.f, 0.f};
        float p0 = 0.f, p1 = 0.f;
        #pragma unroll
        for (int j = 0; j < 4; ++j) {
            const half2_t one = {(_Float16)1.f, (_Float16)1.f};
            half2_t q0 = {af[j][0], af[j][1]}, q1 = {af[j][2], af[j][3]};
            half2_t q2 = {af[j][4], af[j][5]}, q3 = {af[j][6], af[j][7]};
#if __has_builtin(__builtin_amdgcn_fdot2)
            if (j < 2) {
                p0 = __builtin_amdgcn_fdot2(q0, one, p0, false);
                p0 = __builtin_amdgcn_fdot2(q1, one, p0, false);
                p0 = __builtin_amdgcn_fdot2(q2, one, p0, false);
                p0 = __builtin_amdgcn_fdot2(q3, one, p0, false);
            } else {
                p1 = __builtin_amdgcn_fdot2(q0, one, p1, false);
                p1 = __builtin_amdgcn_fdot2(q1, one, p1, false);
                p1 = __builtin_amdgcn_fdot2(q2, one, p1, false);
                p1 = __builtin_amdgcn_fdot2(q3, one, p1, false);
            }
#else
            float acc = (float)af[j][0] + (float)af[j][1] + (float)af[j][2]
                      + (float)af[j][3] + (float)af[j][4] + (float)af[j][5]
                      + (float)af[j][6] + (float)af[j][7];
            if (j < 2) p0 += acc; else p1 += acc;
#endif
            const uint32_t d = bw[j];
            uint4_t bb;
            bb.x = ( d         & 0x000F000Fu) | 0x64006400u;  // nibbles (0,4)
            bb.y = ((d >> 4)   & 0x000F000Fu) | 0x64006400u;  // (1,5)
            bb.z = ((d >> 8)   & 0x000F000Fu) | 0x64006400u;  // (2,6)
            bb.w = ((d >> 12)  & 0x000F000Fu) | 0x64006400u;  // (3,7)
            if ((j & 1) == 0)
                ge = __builtin_amdgcn_mfma_f32_16x16x32_f16(
                         af[j], __builtin_bit_cast(half8_t, bb), ge, 0, 0, 0);
            else
                go = __builtin_amdgcn_mfma_f32_16x16x32_f16(
                         af[j], __builtin_bit_cast(half8_t, bb), go, 0, 0, 0);
        }
        pg[g] = p0 + p1;
        #pragma unroll
        for (int r = 0; r < 4; ++r)
            outacc[r] = fmaf(sA[g], ge[r] + go[r], outacc[r]);
    }

    // ---- epilogue: deferred zero-point correction (shuffles pipeline) ----
    #pragma unroll
    for (int g = 0; g < GPB; ++g) {
        pg[g] += __shfl_xor(pg[g], 16, 64);
        pg[g] += __shfl_xor(pg[g], 32, 64);
    }
    #pragma unroll
    for (int r = 0; r < 4; ++r) {
        float acc = outacc[r];
        #pragma unroll
        for (int g = 0; g < GPB; ++g)
            acc = fmaf(cA[g], __shfl(pg[g], quad * 4 + r, 64), acc);
        // split-k partial -> workspace, plain coalesced store (NO atomics):
        // ws[kq][m = quad*4+r][n]
        ws[((size_t)(kq * MM + quad * 4 + r) * NN) + n] = acc;
    }
}

// ---------------------------------------------------------------------------
extern "C" void kernel_launch(void* const* d_in, const int* in_sizes, int n_in,
                              void* d_out, int out_size, void* d_ws, size_t ws_size,
                              hipStream_t stream) {
    const float* x      = (const float*)d_in[0];   // [16, 8192]
    const int*   qw     = (const int*)d_in[1];     // [8192, 1024]
    const float* scales = (const float*)d_in[2];   // [64, 8192]
    const float* zeros  = (const float*)d_in[3];   // [64, 8192]
    const float* bias   = (const float*)d_in[4];   // [8192]
    float* out = (float*)d_out;                    // [16, 8192] fp32
    float* ws  = (float*)d_ws;                     // 4 MB partials
    (void)ws_size; (void)in_sizes; (void)n_in;

    wq_main<<<NT * KQN, 256, 0, stream>>>(x, qw, scales, zeros, ws);
    wq_reduce<<<MM * NN / (256 * 4), 256, 0, stream>>>(ws, bias, out);
}

// Round 8
// 101.199 us; speedup vs baseline: 1.2714x; 1.2714x over previous
//
#include <hip/hip_runtime.h>
#include <stdint.h>
#include <stddef.h>

// Problem constants (reference: M=16, K=8192, N=8192, GROUP=128)
#define MM 16
#define KK 8192
#define NN 8192
#define GROUP_SZ 128
#define NGROUP 64
#define KPACK 1024           // K/8 packed int32 per output row
#define NT 128               // 64-col n-tiles
#define KQN 8                // k-split factor
#define KSL (KK / KQN)       // 1024 k per block
#define GPB (KSL / GROUP_SZ) // 8 groups per block
#define CPB 64               // n-cols per block

typedef _Float16 half8_t __attribute__((ext_vector_type(8)));
typedef _Float16 half2_t __attribute__((ext_vector_type(2)));
typedef float float4_t __attribute__((ext_vector_type(4)));
typedef uint32_t uint4_t __attribute__((ext_vector_type(4)));

// XOR swizzle on 16B-chunk index within a 256-chunk x-stage buffer.
// Validated in rounds 3-7 (write & read beats both <=2-way, free).
__device__ __forceinline__ int swz(int fc) {
    return fc ^ (((fc >> 3) ^ (fc >> 6)) & 7);
}

// ---------------------------------------------------------------------------
// Reduce: out[m][n] = bias[n] + sum_kq ws[kq][m][n].  128 blocks x 256 thr,
// float4 per thread. Reads 4MB + 32KB, writes 512KB (~1.5us).
// ---------------------------------------------------------------------------
__global__ __launch_bounds__(256) void wq_reduce(const float* __restrict__ ws,
                                                 const float* __restrict__ bias,
                                                 float* __restrict__ out) {
    const int idx = (blockIdx.x * 256 + threadIdx.x) * 4;
    const int m   = idx >> 13;          // NN = 2^13
    const int nn  = idx & (NN - 1);
    float4_t v = *(const float4_t*)(bias + nn);
    #pragma unroll
    for (int kq = 0; kq < KQN; ++kq) {
        const float4_t p = *(const float4_t*)(ws + ((size_t)(kq * MM + m) * NN + nn));
        v[0] += p[0]; v[1] += p[1]; v[2] += p[2]; v[3] += p[3];
    }
    *(float4_t*)(out + (size_t)m * NN + nn) = v;
}

// ---------------------------------------------------------------------------
// 1024 blocks = 128 n-tiles x 8 k-splits; 256 threads (4 waves).
// Block (nt, kq): cols [nt*64, +64), k [kq*1024, +1024) = 8 groups.
//
// qweight: cooperatively streamed into LDS as CONTIGUOUS 512B runs (validated
//   round 6/7: streams at 3.2TB/s vs 0.47 for the strided gather).
// x: staged once per block (shared by all 4 waves), double-buffered,
//   1 barrier/group; validated fragment order/swizzle.
// Math per group identical to the validated round-3..7 kernels.
//
// vs round 7: __launch_bounds__(256, 2) instead of (256, 4). Rounds 6/7's
// (256,4) clamped the allocator to 64 VGPRs against a ~110-VGPR live set ->
// ~88 MB of scratch-spill writes + ~35 MB of reload fetches per dispatch
// (WRITE_SIZE 92 MB vs 4.5 ideal; identical across rounds 6/7, so NOT the
// atomics). Budget 256 VGPRs eliminates scratch entirely; LDS (40 KB)
// still allows 4 blocks/CU when the kernel lands <=128 VGPRs.
// ---------------------------------------------------------------------------
__global__ __launch_bounds__(256, 2) void wq_main(
        const float* __restrict__ x,
        const int* __restrict__ qweight,
        const float* __restrict__ scales,
        const float* __restrict__ zeros,
        float* __restrict__ ws) {
    __shared__ alignas(16) int      qlds[CPB * 128];     // 32 KB (64 rows x 512B)
    __shared__ alignas(16) _Float16 xstage[2 * 2048];    // 8 KB (2 x 4KB bufs)

    const int t    = threadIdx.x;
    const int bid  = blockIdx.x;
    const int nt   = bid & (NT - 1);   // consecutive bids -> different XCDs
    const int kq   = bid >> 7;
    const int w    = t >> 6;
    const int lane = t & 63;
    const int nlo  = lane & 15;
    const int quad = lane >> 4;
    const int n    = nt * CPB + w * 16 + nlo;

    // ---- cooperative qweight stream: 2048 chunks of 16B; chunk c ----
    // rr = c>>5 (row 0..63), b = c&31 (16B piece within 512B row-slice).
    uint4_t qv[8];
    #pragma unroll
    for (int i = 0; i < 8; ++i) {
        const int c  = i * 256 + t;
        const int rr = c >> 5, b = c & 31;
        qv[i] = *(const uint4_t*)(qweight + (size_t)(nt * CPB + rr) * KPACK
                                  + kq * (KSL / 8) + b * 4);
    }

    // ---- x group-0 load (thread t -> row xr, k-oct xo) ----
    const int xr = t >> 4, xo = t & 15;
    const float* xbase = x + (size_t)xr * KK + kq * KSL + xo * 8;
    float4_t pxa = *(const float4_t*)(xbase);
    float4_t pxb = *(const float4_t*)(xbase + 4);

    // ---- hoisted per-group scale / zero-correction coefficients ----
    float sA[GPB], cA[GPB];
    #pragma unroll
    for (int g = 0; g < GPB; ++g) {
        const size_t ro = (size_t)(kq * GPB + g) * NN + n;
        const float sg = scales[ro];
        const float zg = zeros[ro];
        sA[g] = sg;
        cA[g] = zg - 1024.0f * sg;
    }

    // ---- qlds write: row-slice-major, per-row XOR swizzle ----
    #pragma unroll
    for (int i = 0; i < 8; ++i) {
        const int c  = i * 256 + t;
        const int rr = c >> 5, b = c & 31;
        *(uint4_t*)((char*)qlds + ((rr * 32 + (b ^ (rr & 7))) << 4)) = qv[i];
    }

    // ---- stage x group 0 into buf0 (validated fragment order/swizzle) ----
    const int wchunk = swz((xo & 3) * 64 + (xo >> 2) * 16 + xr);
    half8_t* xb = (half8_t*)xstage;
    {
        half8_t st;
        st[0] = (_Float16)pxa[0]; st[1] = (_Float16)pxb[0];
        st[2] = (_Float16)pxa[1]; st[3] = (_Float16)pxb[1];
        st[4] = (_Float16)pxa[2]; st[5] = (_Float16)pxb[2];
        st[6] = (_Float16)pxa[3]; st[7] = (_Float16)pxb[3];
        xb[wchunk] = st;
    }
    // prefetch x group 1
    pxa = *(const float4_t*)(xbase + GROUP_SZ);
    pxb = *(const float4_t*)(xbase + GROUP_SZ + 4);

    int rfc[4];
    #pragma unroll
    for (int j = 0; j < 4; ++j)
        rfc[j] = swz(j * 64 + lane);
    const int qrr = w * 16 + nlo;  // this lane's qlds row

    float4_t outacc = {0.f, 0.f, 0.f, 0.f};
    float pg[GPB];

    #pragma unroll
    for (int g = 0; g < GPB; ++g) {
        // barrier: (a) makes buf[g&1] writes visible, (b) guarantees the
        // previous group's reads of buf[(g+1)&1] are done before overwrite
        __syncthreads();

        if (g + 1 < GPB) {
            half8_t st;
            st[0] = (_Float16)pxa[0]; st[1] = (_Float16)pxb[0];
            st[2] = (_Float16)pxa[1]; st[3] = (_Float16)pxb[1];
            st[4] = (_Float16)pxa[2]; st[5] = (_Float16)pxb[2];
            st[6] = (_Float16)pxa[3]; st[7] = (_Float16)pxb[3];
            xb[(((g + 1) & 1) << 8) + wchunk] = st;
        }
        if (g + 2 < GPB) {
            pxa = *(const float4_t*)(xbase + (g + 2) * GROUP_SZ);
            pxb = *(const float4_t*)(xbase + (g + 2) * GROUP_SZ + 4);
        }

        // B: one ds_read_b128 = 4 packed int32 (k-chunk quad*32..+32)
        const uint4_t bw = *(const uint4_t*)((const char*)qlds
            + ((qrr * 32 + ((g * 4 + quad) ^ (qrr & 7))) << 4));

        // A fragments from the shared staged buffer
        half8_t af[4];
        #pragma unroll
        for (int j = 0; j < 4; ++j)
            af[j] = xb[((g & 1) << 8) + rfc[j]];

        float4_t ge = {0.f, 0.f, 0.f, 0.f};
        float4_t go = {0.f, 0.f, 0.f, 0.f};
        float p0 = 0.f, p1 = 0.f;
        #pragma unroll
        for (int j = 0; j < 4; ++j) {
            const half2_t one = {(_Float16)1.f, (_Float16)1.f};
            half2_t q0 = {af[j][0], af[j][1]}, q1 = {af[j][2], af[j][3]};
            half2_t q2 = {af[j][4], af[j][5]}, q3 = {af[j][6], af[j][7]};
#if __has_builtin(__builtin_amdgcn_fdot2)
            if (j < 2) {
                p0 = __builtin_amdgcn_fdot2(q0, one, p0, false);
                p0 = __builtin_amdgcn_fdot2(q1, one, p0, false);
                p0 = __builtin_amdgcn_fdot2(q2, one, p0, false);
                p0 = __builtin_amdgcn_fdot2(q3, one, p0, false);
            } else {
                p1 = __builtin_amdgcn_fdot2(q0, one, p1, false);
                p1 = __builtin_amdgcn_fdot2(q1, one, p1, false);
                p1 = __builtin_amdgcn_fdot2(q2, one, p1, false);
                p1 = __builtin_amdgcn_fdot2(q3, one, p1, false);
            }
#else
            float acc = (float)af[j][0] + (float)af[j][1] + (float)af[j][2]
                      + (float)af[j][3] + (float)af[j][4] + (float)af[j][5]
                      + (float)af[j][6] + (float)af[j][7];
            if (j < 2) p0 += acc; else p1 += acc;
#endif
            const uint32_t d = bw[j];
            uint4_t bb;
            bb.x = ( d         & 0x000F000Fu) | 0x64006400u;  // nibbles (0,4)
            bb.y = ((d >> 4)   & 0x000F000Fu) | 0x64006400u;  // (1,5)
            bb.z = ((d >> 8)   & 0x000F000Fu) | 0x64006400u;  // (2,6)
            bb.w = ((d >> 12)  & 0x000F000Fu) | 0x64006400u;  // (3,7)
            if ((j & 1) == 0)
                ge = __builtin_amdgcn_mfma_f32_16x16x32_f16(
                         af[j], __builtin_bit_cast(half8_t, bb), ge, 0, 0, 0);
            else
                go = __builtin_amdgcn_mfma_f32_16x16x32_f16(
                         af[j], __builtin_bit_cast(half8_t, bb), go, 0, 0, 0);
        }
        pg[g] = p0 + p1;
        #pragma unroll
        for (int r = 0; r < 4; ++r)
            outacc[r] = fmaf(sA[g], ge[r] + go[r], outacc[r]);
    }

    // ---- epilogue: deferred zero-point correction (shuffles pipeline) ----
    #pragma unroll
    for (int g = 0; g < GPB; ++g) {
        pg[g] += __shfl_xor(pg[g], 16, 64);
        pg[g] += __shfl_xor(pg[g], 32, 64);
    }
    #pragma unroll
    for (int r = 0; r < 4; ++r) {
        float acc = outacc[r];
        #pragma unroll
        for (int g = 0; g < GPB; ++g)
            acc = fmaf(cA[g], __shfl(pg[g], quad * 4 + r, 64), acc);
        // split-k partial -> workspace, plain coalesced store (NO atomics):
        // ws[kq][m = quad*4+r][n]
        ws[((size_t)(kq * MM + quad * 4 + r) * NN) + n] = acc;
    }
}

// ---------------------------------------------------------------------------
extern "C" void kernel_launch(void* const* d_in, const int* in_sizes, int n_in,
                              void* d_out, int out_size, void* d_ws, size_t ws_size,
                              hipStream_t stream) {
    const float* x      = (const float*)d_in[0];   // [16, 8192]
    const int*   qw     = (const int*)d_in[1];     // [8192, 1024]
    const float* scales = (const float*)d_in[2];   // [64, 8192]
    const float* zeros  = (const float*)d_in[3];   // [64, 8192]
    const float* bias   = (const float*)d_in[4];   // [8192]
    float* out = (float*)d_out;                    // [16, 8192] fp32
    float* ws  = (float*)d_ws;                     // 4 MB partials
    (void)ws_size; (void)in_sizes; (void)n_in;

    wq_main<<<NT * KQN, 256, 0, stream>>>(x, qw, scales, zeros, ws);
    wq_reduce<<<MM * NN / (256 * 4), 256, 0, stream>>>(ws, bias, out);
}

// Round 9
// 98.129 us; speedup vs baseline: 1.3112x; 1.0313x over previous
//
#include <hip/hip_runtime.h>
#include <stdint.h>
#include <stddef.h>

// Problem constants (reference: M=16, K=8192, N=8192, GROUP=128)
#define MM 16
#define KK 8192
#define NN 8192
#define GROUP_SZ 128
#define KPACK 1024           // K/8 packed int32 per output row
#define KQN 8                // k-split factor
#define KSL (KK / KQN)       // 1024 k per slice
#define GPB (KSL / GROUP_SZ) // 8 groups per slice
#define TPB 4                // 64-col tiles per block

typedef _Float16 half8_t __attribute__((ext_vector_type(8)));
typedef _Float16 half2_t __attribute__((ext_vector_type(2)));
typedef float float4_t __attribute__((ext_vector_type(4)));
typedef uint32_t uint4_t __attribute__((ext_vector_type(4)));

// XOR swizzle on 16B-chunk index within a 256-chunk x-stage buffer.
// Validated rounds 3-8 (write & read beats both <=2-way, free).
__device__ __forceinline__ int swz(int fc) {
    return fc ^ (((fc >> 3) ^ (fc >> 6)) & 7);
}

// ---------------------------------------------------------------------------
// Reduce: out[m][n] = bias[n] + sum_kq ws[kq][m][n].  128 blocks x 256 thr.
// ---------------------------------------------------------------------------
__global__ __launch_bounds__(256) void wq_reduce(const float* __restrict__ ws,
                                                 const float* __restrict__ bias,
                                                 float* __restrict__ out) {
    const int idx = (blockIdx.x * 256 + threadIdx.x) * 4;
    const int m   = idx >> 13;          // NN = 2^13
    const int nn  = idx & (NN - 1);
    float4_t v = *(const float4_t*)(bias + nn);
    #pragma unroll
    for (int kq = 0; kq < KQN; ++kq) {
        const float4_t p = *(const float4_t*)(ws + ((size_t)(kq * MM + m) * NN + nn));
        v[0] += p[0]; v[1] += p[1]; v[2] += p[2]; v[3] += p[3];
    }
    *(float4_t*)(out + (size_t)m * NN + nn) = v;
}

// ---------------------------------------------------------------------------
// Persistent-CU pipeline: 256 blocks (1/CU) x 256 threads (4 waves).
// Block (ntq, kq): cols [ntq*256, +256) as 4 x 64-col tiles, k-slice
// [kq*1024, +1024) = 8 groups.
//
// All 8 prior structures pinned at 26-33us kernel-side with every pipe idle:
// per-CU outstanding-miss depth (VGPR-staged load bursts at 8 waves/CU)
// capped reads at ~3 TB/s. Fix: qweight staged by global_load_lds DMA
// (no VGPR round-trip; counted vmcnt, never drained mid-loop) with the
// LDS-side XOR swizzle realized by pre-swizzling the per-lane GLOBAL
// source (DMA dest must be linear); x fragments staged ONCE per block
// (shared by 4 tiles); scales/zeros pre-corrected into LDS coalesced.
// Compute math per (group, n) is bit-identical to validated rounds 3-8.
// Stores all deferred after the loop so the vmcnt stream is pure DMA.
// LDS 112 KB -> 1 block/CU. __launch_bounds__(256,1): no spill (R6/7 trap).
// ---------------------------------------------------------------------------
__global__ __launch_bounds__(256, 1) void wq_main(
        const float* __restrict__ x,
        const int* __restrict__ qweight,
        const float* __restrict__ scales,
        const float* __restrict__ zeros,
        float* __restrict__ ws) {
    __shared__ alignas(16) int      qlds[2 * 8192];    // 64 KB: 2 x 32KB tile bufs
    __shared__ alignas(16) _Float16 xfull[8 * 2048];   // 32 KB: 8 group buffers
    __shared__ float sldsS[GPB * 256];                 // 8 KB
    __shared__ float sldsC[GPB * 256];                 // 8 KB (z - 1024*s)

    const int t    = threadIdx.x;
    const int kq   = blockIdx.x & 7;     // same-kq blocks -> same XCD (share x)
    const int ntq  = blockIdx.x >> 3;
    const int w    = t >> 6;
    const int lane = t & 63;
    const int nlo  = lane & 15;
    const int quad = lane >> 4;
    const int hi   = lane >> 5;

    // ---- qweight tile DMA: LDS linear chunk c=(w*8+ii)*64+lane holds
    // global piece b = (c&31) ^ ((c>>5)&7) of row rr = c>>5 (pre-swizzled
    // source => the validated swizzled-read layout, conflict-free B reads).
    auto issue_tile = [&](int i, int bs) {
        const int rowbase = (ntq * TPB + i) * 64;
        #pragma unroll
        for (int ii = 0; ii < 8; ++ii) {
            const int rr = w * 16 + ii * 2 + hi;
            const int b  = (lane & 31) ^ ((ii * 2 + hi) & 7);
            const uint32_t* src = (const uint32_t*)qweight
                + (size_t)(rowbase + rr) * KPACK + kq * 128 + b * 4;
            int* dst = qlds + bs * 8192 + (w * 8 + ii) * 256;
#if __has_builtin(__builtin_amdgcn_global_load_lds)
            __builtin_amdgcn_global_load_lds(
                (const __attribute__((address_space(1))) uint32_t*)src,
                (__attribute__((address_space(3))) uint32_t*)dst, 16, 0, 0);
#else
            *(uint4_t*)(dst + lane * 4) = *(const uint4_t*)src;
#endif
        }
    };

    issue_tile(0, 0);
    issue_tile(1, 1);

    // ---- scales/zeros -> LDS, coalesced; correction folded at stage time
    #pragma unroll
    for (int g = 0; g < GPB; ++g) {
        const size_t ro = (size_t)(kq * GPB + g) * NN + ntq * (TPB * 64) + t;
        const float sg = scales[ro];
        const float zg = zeros[ro];
        sldsS[g * 256 + t] = sg;
        sldsC[g * 256 + t] = zg - 1024.0f * sg;
    }

    // ---- x fragments for the whole k-slice (validated order/swizzle) ----
    const int xr = t >> 4, xo = t & 15;
    const float* xbase = x + (size_t)xr * KK + kq * KSL + xo * 8;
    const int wchunk = swz((xo & 3) * 64 + (xo >> 2) * 16 + xr);
    #pragma unroll
    for (int g = 0; g < GPB; ++g) {
        const float4_t a = *(const float4_t*)(xbase + g * GROUP_SZ);
        const float4_t b = *(const float4_t*)(xbase + g * GROUP_SZ + 4);
        half8_t st;
        st[0] = (_Float16)a[0]; st[1] = (_Float16)b[0];
        st[2] = (_Float16)a[1]; st[3] = (_Float16)b[1];
        st[4] = (_Float16)a[2]; st[5] = (_Float16)b[2];
        st[6] = (_Float16)a[3]; st[7] = (_Float16)b[3];
        ((half8_t*)xfull)[g * 256 + wchunk] = st;
    }

    // tile 0 resident (8 newest = tile 1 stays in flight), LDS writes done
    asm volatile("s_waitcnt vmcnt(8) lgkmcnt(0)" ::: "memory");
    __builtin_amdgcn_sched_barrier(0);
    __builtin_amdgcn_s_barrier();
    __builtin_amdgcn_sched_barrier(0);

    int rfc[4];
    #pragma unroll
    for (int j = 0; j < 4; ++j)
        rfc[j] = swz(j * 64 + lane);
    const int qrr = w * 16 + nlo;

    float4_t outT[TPB];

    #pragma unroll
    for (int i = 0; i < TPB; ++i) {
        const int bs = i & 1;

        float sA[GPB], cA[GPB];
        #pragma unroll
        for (int g = 0; g < GPB; ++g) {
            sA[g] = sldsS[g * 256 + i * 64 + w * 16 + nlo];
            cA[g] = sldsC[g * 256 + i * 64 + w * 16 + nlo];
        }

        float4_t acc = {0.f, 0.f, 0.f, 0.f};
        float pg[GPB];
        #pragma unroll
        for (int g = 0; g < GPB; ++g) {
            // B: ds_read_b128, swizzled chunk (2-way max, validated)
            const uint4_t bw = *(const uint4_t*)(qlds + bs * 8192
                + (qrr * 32 + ((g * 4 + quad) ^ (qrr & 7))) * 4);
            half8_t af[4];
            #pragma unroll
            for (int j = 0; j < 4; ++j)
                af[j] = ((const half8_t*)xfull)[g * 256 + rfc[j]];

            float4_t ge = {0.f, 0.f, 0.f, 0.f};
            float4_t go = {0.f, 0.f, 0.f, 0.f};
            float p0 = 0.f, p1 = 0.f;
            #pragma unroll
            for (int j = 0; j < 4; ++j) {
                const half2_t one = {(_Float16)1.f, (_Float16)1.f};
                half2_t q0 = {af[j][0], af[j][1]}, q1 = {af[j][2], af[j][3]};
                half2_t q2 = {af[j][4], af[j][5]}, q3 = {af[j][6], af[j][7]};
#if __has_builtin(__builtin_amdgcn_fdot2)
                if (j < 2) {
                    p0 = __builtin_amdgcn_fdot2(q0, one, p0, false);
                    p0 = __builtin_amdgcn_fdot2(q1, one, p0, false);
                    p0 = __builtin_amdgcn_fdot2(q2, one, p0, false);
                    p0 = __builtin_amdgcn_fdot2(q3, one, p0, false);
                } else {
                    p1 = __builtin_amdgcn_fdot2(q0, one, p1, false);
                    p1 = __builtin_amdgcn_fdot2(q1, one, p1, false);
                    p1 = __builtin_amdgcn_fdot2(q2, one, p1, false);
                    p1 = __builtin_amdgcn_fdot2(q3, one, p1, false);
                }
#else
                float s8 = (float)af[j][0] + (float)af[j][1] + (float)af[j][2]
                         + (float)af[j][3] + (float)af[j][4] + (float)af[j][5]
                         + (float)af[j][6] + (float)af[j][7];
                if (j < 2) p0 += s8; else p1 += s8;
#endif
                const uint32_t d = bw[j];
                uint4_t bb;
                bb.x = ( d         & 0x000F000Fu) | 0x64006400u;  // nibbles (0,4)
                bb.y = ((d >> 4)   & 0x000F000Fu) | 0x64006400u;  // (1,5)
                bb.z = ((d >> 8)   & 0x000F000Fu) | 0x64006400u;  // (2,6)
                bb.w = ((d >> 12)  & 0x000F000Fu) | 0x64006400u;  // (3,7)
                if ((j & 1) == 0)
                    ge = __builtin_amdgcn_mfma_f32_16x16x32_f16(
                             af[j], __builtin_bit_cast(half8_t, bb), ge, 0, 0, 0);
                else
                    go = __builtin_amdgcn_mfma_f32_16x16x32_f16(
                             af[j], __builtin_bit_cast(half8_t, bb), go, 0, 0, 0);
            }
            pg[g] = p0 + p1;
            #pragma unroll
            for (int r = 0; r < 4; ++r)
                acc[r] = fmaf(sA[g], ge[r] + go[r], acc[r]);
        }

        // all waves done reading qlds[bs] -> safe to refill it
        __builtin_amdgcn_sched_barrier(0);
        __builtin_amdgcn_s_barrier();
        __builtin_amdgcn_sched_barrier(0);
        if (i + 2 < TPB) issue_tile(i + 2, bs);

        // deferred zero-point correction (shuffles overlap the DMA flight)
        #pragma unroll
        for (int g = 0; g < GPB; ++g) {
            pg[g] += __shfl_xor(pg[g], 16, 64);
            pg[g] += __shfl_xor(pg[g], 32, 64);
        }
        #pragma unroll
        for (int r = 0; r < 4; ++r) {
            float a2 = acc[r];
            #pragma unroll
            for (int g = 0; g < GPB; ++g)
                a2 = fmaf(cA[g], __shfl(pg[g], quad * 4 + r, 64), a2);
            acc[r] = a2;
        }
        outT[i] = acc;

        if (i + 1 < TPB) {
            // tile i+1 resident; keep tile i+2 (if any) in flight
            if (i + 2 < TPB)
                asm volatile("s_waitcnt vmcnt(8)" ::: "memory");
            else
                asm volatile("s_waitcnt vmcnt(0)" ::: "memory");
            __builtin_amdgcn_sched_barrier(0);
            __builtin_amdgcn_s_barrier();
            __builtin_amdgcn_sched_barrier(0);
        }
    }

    // ---- all stores deferred here (keeps loop vmcnt stream pure DMA) ----
    #pragma unroll
    for (int i = 0; i < TPB; ++i) {
        const int n = (ntq * TPB + i) * 64 + w * 16 + nlo;
        #pragma unroll
        for (int r = 0; r < 4; ++r)
            ws[(size_t)(kq * MM + quad * 4 + r) * NN + n] = outT[i][r];
    }
}

// ---------------------------------------------------------------------------
extern "C" void kernel_launch(void* const* d_in, const int* in_sizes, int n_in,
                              void* d_out, int out_size, void* d_ws, size_t ws_size,
                              hipStream_t stream) {
    const float* x      = (const float*)d_in[0];   // [16, 8192]
    const int*   qw     = (const int*)d_in[1];     // [8192, 1024]
    const float* scales = (const float*)d_in[2];   // [64, 8192]
    const float* zeros  = (const float*)d_in[3];   // [64, 8192]
    const float* bias   = (const float*)d_in[4];   // [8192]
    float* out = (float*)d_out;                    // [16, 8192] fp32
    float* ws  = (float*)d_ws;                     // 4 MB partials
    (void)ws_size; (void)in_sizes; (void)n_in;

    wq_main<<<256, 256, 0, stream>>>(x, qw, scales, zeros, ws);
    wq_reduce<<<MM * NN / (256 * 4), 256, 0, stream>>>(ws, bias, out);
}

// Round 10
// 94.852 us; speedup vs baseline: 1.3565x; 1.0345x over previous
//
#include <hip/hip_runtime.h>
#include <stdint.h>
#include <stddef.h>

// Problem constants (reference: M=16, K=8192, N=8192, GROUP=128)
#define MM 16
#define KK 8192
#define NN 8192
#define GROUP_SZ 128
#define NGROUP 64            // K / GROUP
#define KPACK 1024           // K / 8 packed int32 per output row
#define NWAVE 8              // waves per block (one K/8 slice each)
#define KCH (KK / NWAVE)     // 1024 k per wave
#define GPW (KCH / GROUP_SZ) // 8 groups per wave
#define CPB 32               // n-cols per block (two 16-col MFMA tiles)

typedef _Float16 half8_t __attribute__((ext_vector_type(8)));
typedef _Float16 half2_t __attribute__((ext_vector_type(2)));
typedef float float4_t __attribute__((ext_vector_type(4)));
typedef uint32_t uint4_t __attribute__((ext_vector_type(4)));

// XOR swizzle on the 16B-chunk index (256 chunks per buffer). Bijective;
// spreads both ds_write_b128 and ds_read_b128 over the 8 bank-groups.
__device__ __forceinline__ int swz(int fc) {
    return fc ^ (((fc >> 3) ^ (fc >> 6)) & 7);
}

// ---------------------------------------------------------------------------
// Session-best kernel (measured 94.6us total in round 5), resubmitted to
// lock in the best result. 256 blocks (one 32-col n-tile-pair) x 512
// threads (8 waves). Wave w owns k-slice [w*1024, (w+1)*1024) = 8 groups,
// amortizing each staged A-fragment over TWO n-tiles (n, n+16).
// Single dispatch, no workspace, direct bias+output store.
//   - x staged per wave through private swizzled LDS (validated r3-9)
//   - qweight: per-lane dwordx4 gathers, full 64B-line utilization/wave
//   - rte f16 cvts + fdot2 exact zero-point sums + f32 group accumulators
//   - deferred epilogue shuffles (r4), double-buffered staging (r4)
//   - launch_bounds(512,2): no VGPR spill (r6/r7 trap measured: 92MB
//     WRITE_SIZE of scratch at (256,4) -> 4.5MB at spill-free budget)
// ---------------------------------------------------------------------------
__global__ __launch_bounds__(512, 2) void wq_fused(
        const float* __restrict__ x,
        const int* __restrict__ qweight,
        const float* __restrict__ scales,
        const float* __restrict__ zeros,
        const float* __restrict__ bias,
        float* __restrict__ out) {
    __shared__ alignas(16) _Float16 stage[NWAVE * 4096]; // 64 KB: 8KB/wave (2 bufs)
    __shared__ float red[2 * NWAVE * 256];               // 16 KB (tile A, tile B)

    const int t     = threadIdx.x;
    const int w     = t >> 6;
    const int lane  = t & 63;
    const int ntile = blockIdx.x;
    const int nlo   = lane & 15;
    const int quad  = lane >> 4;
    const int n0    = ntile * CPB + nlo;        // tile A column
    const int n1    = n0 + 16;                  // tile B column

    // ---- staging geometry (writer side) ----
    const int l4    = lane & 15;
    const int lh    = lane >> 4;
    const int quadw = l4 >> 2;
    const int jj    = l4 & 3;
    const float* xs = x + (size_t)lh * KK + w * KCH + l4 * 8;

    half8_t* sb = (half8_t*)(stage + w * 4096);
    int wfc[4], rfc[4];
    #pragma unroll
    for (int u = 0; u < 4; ++u)
        wfc[u] = swz(jj * 64 + quadw * 16 + 4 * u + lh);
    #pragma unroll
    for (int j = 0; j < 4; ++j)
        rfc[j] = swz(j * 64 + lane);

    // qweight slices for both tiles: row n, ints [w*128, w*128+128)
    const int* qrowA = qweight + (size_t)n0 * KPACK + w * (KCH / 8);
    const int* qrowB = qweight + (size_t)n1 * KPACK + w * (KCH / 8);
    const int g0 = w * GPW;

    // ---- hoisted per-group scale / zero-correction coefficients ----
    float sA0[GPW], cA0[GPW], sA1[GPW], cA1[GPW];
    #pragma unroll
    for (int g = 0; g < GPW; ++g) {
        const size_t ro = (size_t)(g0 + g) * NN;
        const float sa = scales[ro + n0], za = zeros[ro + n0];
        const float sbc = scales[ro + n1], zb = zeros[ro + n1];
        sA0[g] = sa; cA0[g] = za - 1024.0f * sa;
        sA1[g] = sbc; cA1[g] = zb - 1024.0f * sbc;
    }

    // ---- prologue: stage group 0 into buf0, prefetch group 1 ----
    float4_t xa[4], xb[4];
    #pragma unroll
    for (int u = 0; u < 4; ++u) {
        xa[u] = *(const float4_t*)(xs + (size_t)u * 4 * KK);
        xb[u] = *(const float4_t*)(xs + (size_t)u * 4 * KK + 4);
    }
    uint4_t bwcA = *(const uint4_t*)(qrowA + quad * 4);
    uint4_t bwcB = *(const uint4_t*)(qrowB + quad * 4);

    #pragma unroll
    for (int u = 0; u < 4; ++u) {
        half8_t st;
        st[0] = (_Float16)xa[u][0]; st[1] = (_Float16)xb[u][0];
        st[2] = (_Float16)xa[u][1]; st[3] = (_Float16)xb[u][1];
        st[4] = (_Float16)xa[u][2]; st[5] = (_Float16)xb[u][2];
        st[6] = (_Float16)xa[u][3]; st[7] = (_Float16)xb[u][3];
        sb[wfc[u]] = st;
    }
    #pragma unroll
    for (int u = 0; u < 4; ++u) {
        xa[u] = *(const float4_t*)(xs + (size_t)u * 4 * KK + GROUP_SZ);
        xb[u] = *(const float4_t*)(xs + (size_t)u * 4 * KK + GROUP_SZ + 4);
    }
    uint4_t bwnA = *(const uint4_t*)(qrowA + 16 + quad * 4);
    uint4_t bwnB = *(const uint4_t*)(qrowB + 16 + quad * 4);

    float4_t outA = {0.f, 0.f, 0.f, 0.f};
    float4_t outB = {0.f, 0.f, 0.f, 0.f};
    float pg[GPW];

    #pragma unroll
    for (int g = 0; g < GPW; ++g) {
        const int rb = (g & 1) << 8;        // read-buffer chunk offset
        const int wb = ((g + 1) & 1) << 8;  // write-buffer chunk offset

        // fragment reads: buffer filled last iteration (or prologue)
        half8_t af[4];
        #pragma unroll
        for (int j = 0; j < 4; ++j)
            af[j] = sb[rb + rfc[j]];

        // stage group g+1 (cvt of prefetched regs; write->read gap = 1 iter)
        if (g + 1 < GPW) {
            #pragma unroll
            for (int u = 0; u < 4; ++u) {
                half8_t st;
                st[0] = (_Float16)xa[u][0]; st[1] = (_Float16)xb[u][0];
                st[2] = (_Float16)xa[u][1]; st[3] = (_Float16)xb[u][1];
                st[4] = (_Float16)xa[u][2]; st[5] = (_Float16)xb[u][2];
                st[6] = (_Float16)xa[u][3]; st[7] = (_Float16)xb[u][3];
                sb[wb + wfc[u]] = st;
            }
        }
        // prefetch group g+2 x
        if (g + 2 < GPW) {
            #pragma unroll
            for (int u = 0; u < 4; ++u) {
                xa[u] = *(const float4_t*)(xs + (size_t)u * 4 * KK + (g + 2) * GROUP_SZ);
                xb[u] = *(const float4_t*)(xs + (size_t)u * 4 * KK + (g + 2) * GROUP_SZ + 4);
            }
        }

        float4_t gaccA = {0.f, 0.f, 0.f, 0.f};
        float4_t gaccB = {0.f, 0.f, 0.f, 0.f};
        float p0 = 0.f, p1 = 0.f;
        #pragma unroll
        for (int j = 0; j < 4; ++j) {
            const half2_t one = {(_Float16)1.f, (_Float16)1.f};
            half2_t q0 = {af[j][0], af[j][1]}, q1 = {af[j][2], af[j][3]};
            half2_t q2 = {af[j][4], af[j][5]}, q3 = {af[j][6], af[j][7]};
#if __has_builtin(__builtin_amdgcn_fdot2)
            if (j < 2) {
                p0 = __builtin_amdgcn_fdot2(q0, one, p0, false);
                p0 = __builtin_amdgcn_fdot2(q1, one, p0, false);
                p0 = __builtin_amdgcn_fdot2(q2, one, p0, false);
                p0 = __builtin_amdgcn_fdot2(q3, one, p0, false);
            } else {
                p1 = __builtin_amdgcn_fdot2(q0, one, p1, false);
                p1 = __builtin_amdgcn_fdot2(q1, one, p1, false);
                p1 = __builtin_amdgcn_fdot2(q2, one, p1, false);
                p1 = __builtin_amdgcn_fdot2(q3, one, p1, false);
            }
#else
            float acc = (float)af[j][0] + (float)af[j][1] + (float)af[j][2]
                      + (float)af[j][3] + (float)af[j][4] + (float)af[j][5]
                      + (float)af[j][6] + (float)af[j][7];
            if (j < 2) p0 += acc; else p1 += acc;
#endif
            // tile A dequant + MFMA
            {
                const uint32_t d = bwcA[j];
                uint4_t bb;
                bb.x = ( d         & 0x000F000Fu) | 0x64006400u;
                bb.y = ((d >> 4)   & 0x000F000Fu) | 0x64006400u;
                bb.z = ((d >> 8)   & 0x000F000Fu) | 0x64006400u;
                bb.w = ((d >> 12)  & 0x000F000Fu) | 0x64006400u;
                gaccA = __builtin_amdgcn_mfma_f32_16x16x32_f16(
                            af[j], __builtin_bit_cast(half8_t, bb), gaccA, 0, 0, 0);
            }
            // tile B dequant + MFMA (independent chain, interleaves with A)
            {
                const uint32_t d = bwcB[j];
                uint4_t bb;
                bb.x = ( d         & 0x000F000Fu) | 0x64006400u;
                bb.y = ((d >> 4)   & 0x000F000Fu) | 0x64006400u;
                bb.z = ((d >> 8)   & 0x000F000Fu) | 0x64006400u;
                bb.w = ((d >> 12)  & 0x000F000Fu) | 0x64006400u;
                gaccB = __builtin_amdgcn_mfma_f32_16x16x32_f16(
                            af[j], __builtin_bit_cast(half8_t, bb), gaccB, 0, 0, 0);
            }
        }
        pg[g] = p0 + p1;
        #pragma unroll
        for (int r = 0; r < 4; ++r) {
            outA[r] = fmaf(sA0[g], gaccA[r], outA[r]);
            outB[r] = fmaf(sA1[g], gaccB[r], outB[r]);
        }

        // shift B pipelines
        if (g + 1 < GPW) { bwcA = bwnA; bwcB = bwnB; }
        if (g + 2 < GPW) {
            bwnA = *(const uint4_t*)(qrowA + (g + 2) * 16 + quad * 4);
            bwnB = *(const uint4_t*)(qrowB + (g + 2) * 16 + quad * 4);
        }
    }

    // ---- epilogue: deferred zero-point correction (shuffles pipeline) ----
    #pragma unroll
    for (int g = 0; g < GPW; ++g) {
        pg[g] += __shfl_xor(pg[g], 16, 64);
        pg[g] += __shfl_xor(pg[g], 32, 64);
    }
    // outX[r] (D-row m = quad*4+r): add sum_g cX[g] * sxg[m][g]
    // (broadcast carries only the n-independent row sum; reused by both tiles)
    #pragma unroll
    for (int r = 0; r < 4; ++r) {
        float accA = outA[r], accB = outB[r];
        #pragma unroll
        for (int g = 0; g < GPW; ++g) {
            const float sx = __shfl(pg[g], quad * 4 + r, 64);
            accA = fmaf(cA0[g], sx, accA);
            accB = fmaf(cA1[g], sx, accB);
        }
        outA[r] = accA; outB[r] = accB;
    }

    // C/D layout: col = lane&15, row = quad*4 + r
    #pragma unroll
    for (int r = 0; r < 4; ++r) {
        red[w * 256 + (quad * 4 + r) * 16 + nlo]        = outA[r];
        red[2048 + w * 256 + (quad * 4 + r) * 16 + nlo] = outB[r];
    }
    __syncthreads();

    if (t < 256) {
        const int m  = t >> 4;
        const int nn = t & 15;
        float vA = bias[ntile * CPB + nn];
        float vB = bias[ntile * CPB + 16 + nn];
        #pragma unroll
        for (int ww = 0; ww < NWAVE; ++ww) {
            vA += red[ww * 256 + t];
            vB += red[2048 + ww * 256 + t];
        }
        out[(size_t)m * NN + ntile * CPB + nn]      = vA;
        out[(size_t)m * NN + ntile * CPB + 16 + nn] = vB;
    }
}

// ---------------------------------------------------------------------------
extern "C" void kernel_launch(void* const* d_in, const int* in_sizes, int n_in,
                              void* d_out, int out_size, void* d_ws, size_t ws_size,
                              hipStream_t stream) {
    const float* x      = (const float*)d_in[0];   // [16, 8192]
    const int*   qw     = (const int*)d_in[1];     // [8192, 1024]
    const float* scales = (const float*)d_in[2];   // [64, 8192]
    const float* zeros  = (const float*)d_in[3];   // [64, 8192]
    const float* bias   = (const float*)d_in[4];   // [8192]
    float* out = (float*)d_out;                    // [16, 8192] fp32
    (void)d_ws; (void)ws_size; (void)in_sizes; (void)n_in;

    wq_fused<<<NN / CPB, 512, 0, stream>>>(x, qw, scales, zeros, bias, out);
}